// Round 2
// baseline (67.127 us; speedup 1.0000x reference)
//
#include <hip/hip_runtime.h>
#include <hip/hip_bf16.h>

#define VOCAB 30522
#define BZ 32
#define SEQ 2048
#define D 768
#define P 16
#define PLACEHOLDER_ID 1

// Kernel 1: per-row inclusive scan of placeholder mask -> clipped rank array.
// Grid: BZ blocks x 256 threads; each thread owns 8 consecutive positions.
__global__ void rank_kernel(const int* __restrict__ ids, int* __restrict__ rank) {
    const int b = blockIdx.x;
    const int t = threadIdx.x;            // 0..255
    constexpr int CHUNK = SEQ / 256;      // 8
    const int* row = ids + (size_t)b * SEQ;
    const int base = t * CHUNK;

    int m[CHUNK];
    int cnt = 0;
#pragma unroll
    for (int i = 0; i < CHUNK; ++i) {
        m[i] = (row[base + i] == PLACEHOLDER_ID) ? 1 : 0;
        cnt += m[i];
    }

    // inclusive scan of cnt across 256 threads: shfl within wave64, LDS across waves
    const int lane = t & 63;
    const int wave = t >> 6;
    int incl = cnt;
#pragma unroll
    for (int off = 1; off < 64; off <<= 1) {
        int v = __shfl_up(incl, off, 64);
        if (lane >= off) incl += v;
    }
    __shared__ int wsum[4];
    if (lane == 63) wsum[wave] = incl;
    __syncthreads();
    int woff = 0;
    for (int w = 0; w < wave; ++w) woff += wsum[w];

    int run = woff + (incl - cnt);        // exclusive prefix for this thread
    int* rrow = rank + (size_t)b * SEQ;
#pragma unroll
    for (int i = 0; i < CHUNK; ++i) {
        run += m[i];
        int r = run - 1;
        r = r < 0 ? 0 : (r > (P - 1) ? (P - 1) : r);
        rrow[base + i] = r;
    }
}

// Kernel 2: one block per output row; 192 threads x float4 = 768 floats.
__global__ void gather_kernel(const int* __restrict__ ids,
                              const float* __restrict__ emb,
                              const float* __restrict__ prompt,
                              const int* __restrict__ rank,
                              float* __restrict__ out) {
    const int row = blockIdx.x;           // 0 .. BZ*SEQ-1
    const int id = ids[row];
    const float4* src;
    if (id == PLACEHOLDER_ID) {
        src = (const float4*)(prompt + (size_t)rank[row] * D);
    } else {
        src = (const float4*)(emb + (size_t)id * D);
    }
    float4* dst = (float4*)(out + (size_t)row * D);
    dst[threadIdx.x] = src[threadIdx.x];
}

extern "C" void kernel_launch(void* const* d_in, const int* in_sizes, int n_in,
                              void* d_out, int out_size, void* d_ws, size_t ws_size,
                              hipStream_t stream) {
    const int*   ids    = (const int*)d_in[0];     // [BZ, SEQ] int32
    const float* emb    = (const float*)d_in[1];   // [VOCAB, D] f32
    const float* prompt = (const float*)d_in[2];   // [P, D] f32
    float*       out    = (float*)d_out;           // [BZ, SEQ, D] f32
    int*         rank   = (int*)d_ws;              // BZ*SEQ ints = 256 KB

    rank_kernel<<<BZ, 256, 0, stream>>>(ids, rank);
    gather_kernel<<<BZ * SEQ, D / 4, 0, stream>>>(ids, emb, prompt, rank, out);
}

// Round 3
// 67.010 us; speedup vs baseline: 1.0017x; 1.0017x over previous
//
#include <hip/hip_runtime.h>
#include <hip/hip_bf16.h>

#define VOCAB 30522
#define BZ 32
#define SEQ 2048
#define D 768
#define P 16
#define PLACEHOLDER_ID 1

typedef float f32x4 __attribute__((ext_vector_type(4)));

// Kernel 1: per-row inclusive scan of placeholder mask -> clipped rank array.
__global__ void rank_kernel(const int* __restrict__ ids, int* __restrict__ rank) {
    const int b = blockIdx.x;
    const int t = threadIdx.x;            // 0..255
    constexpr int CHUNK = SEQ / 256;      // 8
    const int* row = ids + (size_t)b * SEQ;
    const int base = t * CHUNK;

    int m[CHUNK];
    int cnt = 0;
#pragma unroll
    for (int i = 0; i < CHUNK; ++i) {
        m[i] = (row[base + i] == PLACEHOLDER_ID) ? 1 : 0;
        cnt += m[i];
    }

    const int lane = t & 63;
    const int wave = t >> 6;
    int incl = cnt;
#pragma unroll
    for (int off = 1; off < 64; off <<= 1) {
        int v = __shfl_up(incl, off, 64);
        if (lane >= off) incl += v;
    }
    __shared__ int wsum[4];
    if (lane == 63) wsum[wave] = incl;
    __syncthreads();
    int woff = 0;
    for (int w = 0; w < wave; ++w) woff += wsum[w];

    int run = woff + (incl - cnt);        // exclusive prefix for this thread
    int* rrow = rank + (size_t)b * SEQ;
#pragma unroll
    for (int i = 0; i < CHUNK; ++i) {
        run += m[i];
        int r = run - 1;
        r = r < 0 ? 0 : (r > (P - 1) ? (P - 1) : r);
        rrow[base + i] = r;
    }
}

// Kernel 2: one 256-thread block per 16 output rows.
// 16 rows x 192 float4 = 3072 float4 = 12 per thread, all loads issued
// before any store (MLP=12). Row source pointers hoisted to LDS.
// Non-temporal stores keep emb_table resident in L3.
#define ROWS_PER_BLOCK 16
__global__ __launch_bounds__(256) void gather_kernel(
        const int* __restrict__ ids,
        const float* __restrict__ emb,
        const float* __restrict__ prompt,
        const int* __restrict__ rank,
        float* __restrict__ out) {
    constexpr int NF4 = D / 4;            // 192 float4 per row
    constexpr int F4_PER_BLOCK = ROWS_PER_BLOCK * NF4;   // 3072
    constexpr int ITERS = F4_PER_BLOCK / 256;            // 12

    const int t = threadIdx.x;
    const int row0 = blockIdx.x * ROWS_PER_BLOCK;

    __shared__ const f32x4* srcs[ROWS_PER_BLOCK];
    if (t < ROWS_PER_BLOCK) {
        const int id = ids[row0 + t];
        srcs[t] = (id == PLACEHOLDER_ID)
                      ? (const f32x4*)(prompt + (size_t)rank[row0 + t] * D)
                      : (const f32x4*)(emb + (size_t)id * D);
    }
    __syncthreads();

    f32x4* dst = (f32x4*)(out + (size_t)row0 * D);

    f32x4 v[ITERS];
#pragma unroll
    for (int k = 0; k < ITERS; ++k) {
        const int f = k * 256 + t;        // 0..3071
        const int r = f / NF4;            // 0..15 (magic-mul div)
        const int c = f - r * NF4;
        v[k] = srcs[r][c];
    }
#pragma unroll
    for (int k = 0; k < ITERS; ++k) {
        __builtin_nontemporal_store(v[k], &dst[k * 256 + t]);
    }
}

extern "C" void kernel_launch(void* const* d_in, const int* in_sizes, int n_in,
                              void* d_out, int out_size, void* d_ws, size_t ws_size,
                              hipStream_t stream) {
    const int*   ids    = (const int*)d_in[0];     // [BZ, SEQ] int32
    const float* emb    = (const float*)d_in[1];   // [VOCAB, D] f32
    const float* prompt = (const float*)d_in[2];   // [P, D] f32
    float*       out    = (float*)d_out;           // [BZ, SEQ, D] f32
    int*         rank   = (int*)d_ws;              // BZ*SEQ ints = 256 KB

    rank_kernel<<<BZ, 256, 0, stream>>>(ids, rank);
    gather_kernel<<<(BZ * SEQ) / ROWS_PER_BLOCK, 256, 0, stream>>>(
        ids, emb, prompt, rank, out);
}

// Round 4
// 63.545 us; speedup vs baseline: 1.0564x; 1.0545x over previous
//
#include <hip/hip_runtime.h>
#include <hip/hip_bf16.h>

#define VOCAB 30522
#define BZ 32
#define SEQ 2048
#define D 768
#define P 16
#define PLACEHOLDER_ID 1
#define ROWS_PER_BLOCK 16

typedef float f32x4 __attribute__((ext_vector_type(4)));

// Single fused kernel. One 256-thread block per 16 consecutive output rows
// (all within one batch row: SEQ/ROWS_PER_BLOCK = 128 blocks per batch row).
// Blocks containing a placeholder id compute the rank inline by scanning
// their batch row's ids (8 KB, L2-resident).
__global__ __launch_bounds__(256) void fused_gather_kernel(
        const int* __restrict__ ids,
        const float* __restrict__ emb,
        const float* __restrict__ prompt,
        float* __restrict__ out) {
    constexpr int NF4 = D / 4;                           // 192 float4 per row
    constexpr int ITERS = ROWS_PER_BLOCK * NF4 / 256;    // 12

    const int t = threadIdx.x;
    const int row0 = blockIdx.x * ROWS_PER_BLOCK;        // global row index
    const int b = row0 / SEQ;
    const int s0 = row0 - b * SEQ;                       // seq offset of first row

    __shared__ int blk_ids[ROWS_PER_BLOCK];
    __shared__ int has_ph;
    __shared__ const f32x4* srcs[ROWS_PER_BLOCK];
    __shared__ int wred[4];

    if (t == 0) has_ph = 0;
    __syncthreads();
    if (t < ROWS_PER_BLOCK) {
        const int id = ids[row0 + t];
        blk_ids[t] = id;
        if (id == PLACEHOLDER_ID) atomicOr(&has_ph, 1);
    }
    __syncthreads();

    if (has_ph) {
        // count placeholders in ids[b][0..s0) across 256 threads (8 pos each)
        const int* row = ids + (size_t)b * SEQ;
        const int p0 = t * 8;
        int cnt = 0;
#pragma unroll
        for (int i = 0; i < 8; ++i) {
            const int p = p0 + i;
            if (p < s0) cnt += (row[p] == PLACEHOLDER_ID) ? 1 : 0;
        }
#pragma unroll
        for (int off = 32; off; off >>= 1) cnt += __shfl_xor(cnt, off, 64);
        const int lane = t & 63, wave = t >> 6;
        if (lane == 0) wred[wave] = cnt;
        __syncthreads();
        if (t < ROWS_PER_BLOCK) {
            int run = wred[0] + wred[1] + wred[2] + wred[3]; // placeholders < s0
            for (int j = 0; j < t; ++j)
                run += (blk_ids[j] == PLACEHOLDER_ID) ? 1 : 0;
            // for a placeholder at row t: rank = count of placeholders before it
            int r = run > (P - 1) ? (P - 1) : run;
            const int id = blk_ids[t];
            srcs[t] = (id == PLACEHOLDER_ID)
                          ? (const f32x4*)(prompt + (size_t)r * D)
                          : (const f32x4*)(emb + (size_t)id * D);
        }
    } else {
        if (t < ROWS_PER_BLOCK) {
            srcs[t] = (const f32x4*)(emb + (size_t)blk_ids[t] * D);
        }
    }
    __syncthreads();

    f32x4* dst = (f32x4*)(out + (size_t)row0 * D);
    f32x4 v[ITERS];
#pragma unroll
    for (int k = 0; k < ITERS; ++k) {
        const int f = k * 256 + t;        // 0..3071
        const int r = f / NF4;
        const int c = f - r * NF4;
        v[k] = srcs[r][c];
    }
#pragma unroll
    for (int k = 0; k < ITERS; ++k) {
        __builtin_nontemporal_store(v[k], &dst[k * 256 + t]);
    }
}

extern "C" void kernel_launch(void* const* d_in, const int* in_sizes, int n_in,
                              void* d_out, int out_size, void* d_ws, size_t ws_size,
                              hipStream_t stream) {
    const int*   ids    = (const int*)d_in[0];     // [BZ, SEQ] int32
    const float* emb    = (const float*)d_in[1];   // [VOCAB, D] f32
    const float* prompt = (const float*)d_in[2];   // [P, D] f32
    float*       out    = (float*)d_out;           // [BZ, SEQ, D] f32

    fused_gather_kernel<<<(BZ * SEQ) / ROWS_PER_BLOCK, 256, 0, stream>>>(
        ids, emb, prompt, out);
}